// Round 4
// baseline (350.107 us; speedup 1.0000x reference)
//
#include <hip/hip_runtime.h>

typedef unsigned short u16;
typedef __attribute__((ext_vector_type(8))) short short8;
typedef __attribute__((ext_vector_type(4))) float f32x4;
typedef __attribute__((ext_vector_type(4))) float floatx4;
typedef __attribute__((ext_vector_type(4))) unsigned short ushort4v;
typedef __attribute__((ext_vector_type(8))) unsigned short ushort8v;
typedef __attribute__((ext_vector_type(4))) unsigned int uint4v;

#define MFMA(a, b, c) __builtin_amdgcn_mfma_f32_16x16x32_bf16(a, b, c, 0, 0, 0)

__device__ __forceinline__ u16 f2bf(float f) {
    unsigned u = __float_as_uint(f);
    u += 0x7fffu + ((u >> 16) & 1u);   // RNE
    return (u16)(u >> 16);
}

__device__ __forceinline__ void async16(const void* g, void* l) {
    __builtin_amdgcn_global_load_lds(
        (const __attribute__((address_space(1))) void*)g,
        (__attribute__((address_space(3))) void*)l, 16, 0, 0);
}

// ---------------- fp32 -> bf16 convert, float4 vectorized ----------------
__global__ void cvt_bf16(const float* __restrict__ s, u16* __restrict__ d, int n4) {
    int i = blockIdx.x * blockDim.x + threadIdx.x;
    int stride = gridDim.x * blockDim.x;
    for (; i < n4; i += stride) {
        floatx4 v = ((const floatx4*)s)[i];
        ushort4v o;
        o[0] = f2bf(v[0]); o[1] = f2bf(v[1]); o[2] = f2bf(v[2]); o[3] = f2bf(v[3]);
        ((ushort4v*)d)[i] = o;
    }
}

// convert the 4 weight matrices in one launch (blockIdx.y selects matrix)
__global__ void cvt4_bf16(const float* __restrict__ s0, const float* __restrict__ s1,
                          const float* __restrict__ s2, const float* __restrict__ s3,
                          u16* __restrict__ d, int n4) {
    const float* s = blockIdx.y == 0 ? s0 : (blockIdx.y == 1 ? s1 : (blockIdx.y == 2 ? s2 : s3));
    u16* dd = d + (size_t)blockIdx.y * n4 * 4;
    int i = blockIdx.x * blockDim.x + threadIdx.x;
    int stride = gridDim.x * blockDim.x;
    for (; i < n4; i += stride) {
        floatx4 v = ((const floatx4*)s)[i];
        ushort4v o;
        o[0] = f2bf(v[0]); o[1] = f2bf(v[1]); o[2] = f2bf(v[2]); o[3] = f2bf(v[3]);
        ((ushort4v*)dd)[i] = o;
    }
}

// ---------------- NT GEMM: C[M,N] = A[M,K] * B[N,K]^T ------------------
// 128x128 tile, BK=64 (32 MFMA per barrier pair), global_load_lds width 16,
// 2x2 waves, 4x4 acc/wave. Rows are 8 chunks of 16B; chunk slot s of row r
// holds global chunk s^(r&7) -> ds_read_b128 2-way max (free), async writes
// still cover full 128B rows (coalesced).
template <bool BF16_OUT>
__global__ __launch_bounds__(256) void gemm_nt(
    const u16* __restrict__ A, const u16* __restrict__ B0,
    const u16* __restrict__ B1, const u16* __restrict__ B2,
    void* __restrict__ Cv, int M, int N, int K)
{
    __shared__ u16 As[128 * 64];
    __shared__ u16 Bs[128 * 64];
    const int tid = threadIdx.x;
    const int wave = tid >> 6, lane = tid & 63;
    const int quad = lane >> 4, tl = lane & 15;
    const int m0 = blockIdx.x * 128, n0 = blockIdx.y * 128;
    const int wm = wave >> 1, wn = wave & 1;
    const u16* Bm = blockIdx.z == 0 ? B0 : (blockIdx.z == 1 ? B1 : B2);
    const size_t coff = (size_t)blockIdx.z * M * N;

    f32x4 acc[4][4];
#pragma unroll
    for (int i = 0; i < 4; i++)
#pragma unroll
        for (int j = 0; j < 4; j++) acc[i][j] = (f32x4)(0.0f);

    // per-thread staging chunk (1024 chunks per matrix, 4 instr each)
    const int srow = tid >> 3, sslot = tid & 7;

    for (int k0 = 0; k0 < K; k0 += 64) {
#pragma unroll
        for (int i = 0; i < 4; i++) {
            int row = i * 32 + srow;                 // ch = i*256+tid; row = ch>>3
            int g = sslot ^ (row & 7);               // global chunk held at this slot
            int ldsbase = (i * 256 + wave * 64) * 8; // wave-uniform dest (u16)
            async16(A  + (size_t)(m0 + row) * K + k0 + g * 8, (u16*)As + ldsbase);
            async16(Bm + (size_t)(n0 + row) * K + k0 + g * 8, (u16*)Bs + ldsbase);
        }
        __syncthreads();
#pragma unroll
        for (int h = 0; h < 2; h++) {
            short8 af[4], bg[4];
            const int rs = (((h * 4 + quad) ^ (tl & 7)) * 8);
#pragma unroll
            for (int t = 0; t < 4; t++) {
                af[t] = *(const short8*)&As[(wm * 64 + t * 16 + tl) * 64 + rs];
                bg[t] = *(const short8*)&Bs[(wn * 64 + t * 16 + tl) * 64 + rs];
            }
#pragma unroll
            for (int mt = 0; mt < 4; mt++)
#pragma unroll
                for (int nt = 0; nt < 4; nt++)
                    acc[mt][nt] = MFMA(af[mt], bg[nt], acc[mt][nt]);
        }
        __syncthreads();
    }

    // epilogue: C/D layout col=lane&15, row=quad*4+reg
#pragma unroll
    for (int mt = 0; mt < 4; mt++)
#pragma unroll
        for (int nt = 0; nt < 4; nt++)
#pragma unroll
            for (int r = 0; r < 4; r++) {
                int row = m0 + wm * 64 + mt * 16 + quad * 4 + r;
                int col = n0 + wn * 64 + nt * 16 + tl;
                if constexpr (BF16_OUT)
                    ((u16*)Cv)[coff + (size_t)row * N + col] = f2bf(acc[mt][nt][r]);
                else
                    ((float*)Cv)[coff + (size_t)row * N + col] = acc[mt][nt][r];
            }
}

// ---------------- fused windowed attention (one block per window) ----------
// Block = (b, h, window): 128 queries, 192 keys (64 global + 128 local).
// 3 barriers total: stage V -> transpose V -> stage K. P never touches LDS:
// the S^T C-layout (lane: query=tl, keys quad*4+r) is converted to the PV
// A-operand layout (keys quad*8+j) with 8 ds_bpermute + 4 selects per 32-key
// chunk. LDS = Vt 25.6K + KP 24.6K = 50.2 KB -> 3 blocks/CU.
__global__ __launch_bounds__(256) void attn_win(
    const u16* __restrict__ qkv, u16* __restrict__ outb)
{
    constexpr int T = 8192, D = 1024, HD = 64, G = 64, WIN = 128;
    constexpr int MTOT = 2 * T;
    __shared__ u16 Vt[64 * 200];   // V^T [dim][key], stride 200
    __shared__ u16 KP[192 * 64];   // union: Vs[192][64] packed -> Ks[192][64] swizzled

    const int blk = blockIdx.x;
    const int nwin = blk & 63;
    const int h = (blk >> 6) & 15;
    const int b = blk >> 10;
    const int tid = threadIdx.x;
    const int wave = tid >> 6, lane = tid & 63;
    const int quad = lane >> 4, tl = lane & 15;
    const int win0 = nwin * WIN;
    const size_t brow = (size_t)b * T;
    const u16* qb = qkv;
    const u16* kb = qkv + (size_t)MTOT * D;
    const u16* vb = qkv + (size_t)2 * MTOT * D;

    // phase 1: stage V packed [key][dim] (contiguous DMA dest)
#pragma unroll
    for (int i = 0; i < 6; i++) {
        int ch = i * 256 + tid;
        int row = ch >> 3, c = ch & 7;
        int tok = row < G ? row : win0 + (row - G);
        async16(vb + (brow + tok) * D + h * HD + c * 8,
                (u16*)KP + (i * 256 + wave * 64) * 8);
    }

    // q fragments (B-operand of S^T): wave owns query tiles wave*2, wave*2+1
    short8 bq[2][2];
#pragma unroll
    for (int qt = 0; qt < 2; qt++) {
        int tok = win0 + (wave * 2 + qt) * 16 + tl;
        const u16* qrow = qb + (brow + tok) * D + h * HD;
        bq[qt][0] = *(const short8*)(qrow + quad * 8);
        bq[qt][1] = *(const short8*)(qrow + 32 + quad * 8);
    }

    __syncthreads();   // V landed

    // phase 2: transpose Vs[key][dim] -> Vt[dim][key]
    {
        const int d = lane;
#pragma unroll
        for (int i = 0; i < 6; i++) {
            int c = i * 4 + wave;   // key-chunk 0..23
            ushort8v v;
#pragma unroll
            for (int j = 0; j < 8; j++) v[j] = KP[(c * 8 + j) * 64 + d];
            *(ushort8v*)&Vt[d * 200 + c * 8] = v;
        }
    }

    __syncthreads();   // Vt ready, KP free

    // phase 3: stage K into KP, swizzled slot = g ^ (row&7)
#pragma unroll
    for (int i = 0; i < 6; i++) {
        int ch = i * 256 + tid;
        int row = ch >> 3, slot = ch & 7;
        int g = slot ^ (row & 7);
        int tok = row < G ? row : win0 + (row - G);
        async16(kb + (brow + tok) * D + h * HD + g * 8,
                (u16*)KP + (i * 256 + wave * 64) * 8);
    }

    __syncthreads();   // K landed

    const float c1 = 0.125f * 1.4426950408889634f;  // scale * log2(e)
    const int s0sl = quad ^ (tl & 7);
    const int s1sl = (4 + quad) ^ (tl & 7);
    const int tsel = quad >> 1;
    const int src0 = tl + 32 * (quad & 1);

#pragma unroll
    for (int qt = 0; qt < 2; qt++) {
        // S^T = K q^T : 12 key-tiles, K frags from LDS (swizzled, conflict-free)
        f32x4 s[12];
#pragma unroll
        for (int kt = 0; kt < 12; kt++) s[kt] = (f32x4)(0.0f);
#pragma unroll
        for (int kt = 0; kt < 12; kt++) {
            int row = kt * 16 + tl;
            short8 a0 = *(const short8*)&KP[row * 64 + s0sl * 8];
            short8 a1 = *(const short8*)&KP[row * 64 + s1sl * 8];
            s[kt] = MFMA(a0, bq[qt][0], s[kt]);
            s[kt] = MFMA(a1, bq[qt][1], s[kt]);
        }

        // softmax over 192 keys for query col=tl: 48 in-lane + 2 quad shuffles
        float mx = -1e30f;
#pragma unroll
        for (int kt = 0; kt < 12; kt++)
#pragma unroll
            for (int r = 0; r < 4; r++) mx = fmaxf(mx, s[kt][r]);
        mx = fmaxf(mx, __shfl_xor(mx, 16, 64));
        mx = fmaxf(mx, __shfl_xor(mx, 32, 64));
        float sum = 0.f;
#pragma unroll
        for (int kt = 0; kt < 12; kt++)
#pragma unroll
            for (int r = 0; r < 4; r++) {
                float e = exp2f((s[kt][r] - mx) * c1);
                s[kt][r] = e;
                sum += e;
            }
        sum += __shfl_xor(sum, 16, 64);
        sum += __shfl_xor(sum, 32, 64);
        float inv = 1.f / sum;

        // pack normalized P as bf16 pairs: pk0 = keys (quad*4+0,+1), pk1 = (+2,+3)
        unsigned pk0[12], pk1[12];
#pragma unroll
        for (int kt = 0; kt < 12; kt++) {
            pk0[kt] = (unsigned)f2bf(s[kt][0] * inv) | ((unsigned)f2bf(s[kt][1] * inv) << 16);
            pk1[kt] = (unsigned)f2bf(s[kt][2] * inv) | ((unsigned)f2bf(s[kt][3] * inv) << 16);
        }

        // PV: per 32-key chunk c (tiles 2c,2c+1), build A-frag in-register:
        // dest lane (quad q, tl) holds query tl, keys q*8+0..7 of tile q>>1:
        //   regs {0,1} from src lane tl+32(q&1)   (its pk0,pk1)
        //   regs {2,3} from src lane tl+32(q&1)+16
        // tile selected on dest side (both tiles shuffled, cndmask by tsel).
        f32x4 o[4];
#pragma unroll
        for (int dt = 0; dt < 4; dt++) o[dt] = (f32x4)(0.0f);
#pragma unroll
        for (int c = 0; c < 6; c++) {
            unsigned f0a = (unsigned)__shfl((int)pk0[2 * c],     src0,      64);
            unsigned f0b = (unsigned)__shfl((int)pk0[2 * c + 1], src0,      64);
            unsigned f1a = (unsigned)__shfl((int)pk1[2 * c],     src0,      64);
            unsigned f1b = (unsigned)__shfl((int)pk1[2 * c + 1], src0,      64);
            unsigned f2a = (unsigned)__shfl((int)pk0[2 * c],     src0 + 16, 64);
            unsigned f2b = (unsigned)__shfl((int)pk0[2 * c + 1], src0 + 16, 64);
            unsigned f3a = (unsigned)__shfl((int)pk1[2 * c],     src0 + 16, 64);
            unsigned f3b = (unsigned)__shfl((int)pk1[2 * c + 1], src0 + 16, 64);
            uint4v fr;
            fr[0] = tsel ? f0b : f0a;
            fr[1] = tsel ? f1b : f1a;
            fr[2] = tsel ? f2b : f2a;
            fr[3] = tsel ? f3b : f3a;
            short8 pa = __builtin_bit_cast(short8, fr);
#pragma unroll
            for (int dt = 0; dt < 4; dt++) {
                short8 vv = *(const short8*)&Vt[(dt * 16 + tl) * 200 + c * 32 + quad * 8];
                o[dt] = MFMA(pa, vv, o[dt]);
            }
        }

        // epilogue: D[m=query][n=dim], row=quad*4+r, col=tl
#pragma unroll
        for (int dt = 0; dt < 4; dt++)
#pragma unroll
            for (int r = 0; r < 4; r++) {
                int qq = win0 + (wave * 2 + qt) * 16 + quad * 4 + r;
                int dim = dt * 16 + tl;
                outb[(brow + qq) * D + h * HD + dim] = f2bf(o[dt][r]);
            }
    }
}

extern "C" void kernel_launch(void* const* d_in, const int* in_sizes, int n_in,
                              void* d_out, int out_size, void* d_ws, size_t ws_size,
                              hipStream_t stream)
{
    const float* x  = (const float*)d_in[0];
    const float* Wq = (const float*)d_in[1];
    const float* Wk = (const float*)d_in[2];
    const float* Wv = (const float*)d_in[3];
    const float* Wo = (const float*)d_in[4];

    const int M = 16384, D = 1024;   // M = B*T
    u16* xb  = (u16*)d_ws;                  // M*D
    u16* wqb = xb  + (size_t)M * D;         // D*D each (q,k,v,o contiguous)
    u16* wob = wqb + (size_t)3 * D * D;
    u16* qkv = wob + (size_t)D * D;         // 3*M*D (q,k,v)
    u16* att = qkv + (size_t)3 * M * D;     // M*D

    cvt_bf16<<<2048, 256, 0, stream>>>(x, xb, M * D / 4);
    cvt4_bf16<<<dim3(64, 4), 256, 0, stream>>>(Wq, Wk, Wv, Wo, wqb, D * D / 4);

    gemm_nt<true ><<<dim3(M / 128, D / 128, 3), 256, 0, stream>>>(
        xb, wqb, wqb + (size_t)D * D, wqb + (size_t)2 * D * D, qkv, M, D, D);
    attn_win<<<dim3(2048), 256, 0, stream>>>(qkv, att);
    gemm_nt<false><<<dim3(M / 128, D / 128, 1), 256, 0, stream>>>(
        att, wob, wob, wob, d_out, M, D, D);
}

// Round 5
// 337.208 us; speedup vs baseline: 1.0383x; 1.0383x over previous
//
#include <hip/hip_runtime.h>

typedef unsigned short u16;
typedef __attribute__((ext_vector_type(8))) short short8;
typedef __attribute__((ext_vector_type(4))) float f32x4;
typedef __attribute__((ext_vector_type(4))) float floatx4;
typedef __attribute__((ext_vector_type(4))) unsigned short ushort4v;
typedef __attribute__((ext_vector_type(8))) unsigned short ushort8v;

#define MFMA(a, b, c) __builtin_amdgcn_mfma_f32_16x16x32_bf16(a, b, c, 0, 0, 0)

__device__ __forceinline__ u16 f2bf(float f) {
    unsigned u = __float_as_uint(f);
    u += 0x7fffu + ((u >> 16) & 1u);   // RNE
    return (u16)(u >> 16);
}

__device__ __forceinline__ void async16(const void* g, void* l) {
    __builtin_amdgcn_global_load_lds(
        (const __attribute__((address_space(1))) void*)g,
        (__attribute__((address_space(3))) void*)l, 16, 0, 0);
}

// ------- fp32 -> bf16 convert: x + 4 weight matrices in ONE launch --------
// dst regions are contiguous (xb | wq | wk | wv | wo), sources separate.
__global__ void cvt_all(const float* __restrict__ x,
                        const float* __restrict__ w0, const float* __restrict__ w1,
                        const float* __restrict__ w2, const float* __restrict__ w3,
                        u16* __restrict__ d, int nx4, int nw4) {
    int total = nx4 + 4 * nw4;
    int i = blockIdx.x * blockDim.x + threadIdx.x;
    int stride = gridDim.x * blockDim.x;
    for (; i < total; i += stride) {
        floatx4 v;
        if (i < nx4) {
            v = ((const floatx4*)x)[i];
        } else {
            int t = i - nx4;
            int w = t >> 18;             // nw4 = 2^18
            int j = t & (nw4 - 1);
            const float* s = w == 0 ? w0 : (w == 1 ? w1 : (w == 2 ? w2 : w3));
            v = ((const floatx4*)s)[j];
        }
        ushort4v o;
        o[0] = f2bf(v[0]); o[1] = f2bf(v[1]); o[2] = f2bf(v[2]); o[3] = f2bf(v[3]);
        ((ushort4v*)d)[i] = o;
    }
}

// ---------------- NT GEMM: C[M,N] = A[M,K] * B[N,K]^T ------------------
// 128x128 tile, BK=64 (32 MFMA per barrier pair), global_load_lds width 16,
// 2x2 waves, 4x4 acc/wave. Rows are 8 chunks of 16B; chunk slot s of row r
// holds global chunk s^(r&7) -> ds_read_b128 2-way max (free), async writes
// still cover full 128B rows (coalesced).
template <bool BF16_OUT>
__global__ __launch_bounds__(256) void gemm_nt(
    const u16* __restrict__ A, const u16* __restrict__ B0,
    const u16* __restrict__ B1, const u16* __restrict__ B2,
    void* __restrict__ Cv, int M, int N, int K)
{
    __shared__ u16 As[128 * 64];
    __shared__ u16 Bs[128 * 64];
    const int tid = threadIdx.x;
    const int wave = tid >> 6, lane = tid & 63;
    const int quad = lane >> 4, tl = lane & 15;
    const int m0 = blockIdx.x * 128, n0 = blockIdx.y * 128;
    const int wm = wave >> 1, wn = wave & 1;
    const u16* Bm = blockIdx.z == 0 ? B0 : (blockIdx.z == 1 ? B1 : B2);
    const size_t coff = (size_t)blockIdx.z * M * N;

    f32x4 acc[4][4];
#pragma unroll
    for (int i = 0; i < 4; i++)
#pragma unroll
        for (int j = 0; j < 4; j++) acc[i][j] = (f32x4)(0.0f);

    // per-thread staging chunk (1024 chunks per matrix, 4 instr each)
    const int srow = tid >> 3, sslot = tid & 7;

    for (int k0 = 0; k0 < K; k0 += 64) {
#pragma unroll
        for (int i = 0; i < 4; i++) {
            int row = i * 32 + srow;                 // ch = i*256+tid; row = ch>>3
            int g = sslot ^ (row & 7);               // global chunk held at this slot
            int ldsbase = (i * 256 + wave * 64) * 8; // wave-uniform dest (u16)
            async16(A  + (size_t)(m0 + row) * K + k0 + g * 8, (u16*)As + ldsbase);
            async16(Bm + (size_t)(n0 + row) * K + k0 + g * 8, (u16*)Bs + ldsbase);
        }
        __syncthreads();
#pragma unroll
        for (int h = 0; h < 2; h++) {
            short8 af[4], bg[4];
            const int rs = (((h * 4 + quad) ^ (tl & 7)) * 8);
#pragma unroll
            for (int t = 0; t < 4; t++) {
                af[t] = *(const short8*)&As[(wm * 64 + t * 16 + tl) * 64 + rs];
                bg[t] = *(const short8*)&Bs[(wn * 64 + t * 16 + tl) * 64 + rs];
            }
#pragma unroll
            for (int mt = 0; mt < 4; mt++)
#pragma unroll
                for (int nt = 0; nt < 4; nt++)
                    acc[mt][nt] = MFMA(af[mt], bg[nt], acc[mt][nt]);
        }
        __syncthreads();
    }

    // epilogue: C/D layout col=lane&15, row=quad*4+reg
#pragma unroll
    for (int mt = 0; mt < 4; mt++)
#pragma unroll
        for (int nt = 0; nt < 4; nt++)
#pragma unroll
            for (int r = 0; r < 4; r++) {
                int row = m0 + wm * 64 + mt * 16 + quad * 4 + r;
                int col = n0 + wn * 64 + nt * 16 + tl;
                if constexpr (BF16_OUT)
                    ((u16*)Cv)[coff + (size_t)row * N + col] = f2bf(acc[mt][nt][r]);
                else
                    ((float*)Cv)[coff + (size_t)row * N + col] = acc[mt][nt][r];
            }
}

// ---------------- fused windowed attention (R3 structure) ----------------
// One block per (b, h, window, half): 64 queries, 192 keys (64 global + 128
// local). V async-staged packed [key][dim] into KP, transposed LDS->LDS into
// Vt, then K async-staged into KP (XOR-swizzled); P reuses KP. S^T = K q^T so
// MFMA C-layout in-lane contiguity runs along keys (2-shuffle softmax).
// P/Vt reads: bank group = 4*((tl+quad) mod 8) -> uniform, no excess conflict.
__global__ __launch_bounds__(256) void attn_win(
    const u16* __restrict__ qkv, u16* __restrict__ outb)
{
    constexpr int T = 8192, D = 1024, HD = 64, G = 64, WIN = 128;
    constexpr int MTOT = 2 * T;
    __shared__ u16 Vt[64 * 200];   // V^T [dim][key], stride 200
    __shared__ u16 KP[12800];      // union: Vs[192][64] -> Ks[192][64] -> Pl[64][200]

    const int blk = blockIdx.x;
    const int half = blk & 1;
    const int nwin = (blk >> 1) & 63;
    const int h = (blk >> 7) & 15;
    const int b = blk >> 11;
    const int tid = threadIdx.x;
    const int wave = tid >> 6, lane = tid & 63;
    const int quad = lane >> 4, tl = lane & 15;
    const int win0 = nwin * WIN;
    const int q0 = win0 + half * 64;
    const size_t brow = (size_t)b * T;
    const u16* qb = qkv;
    const u16* kb = qkv + (size_t)MTOT * D;
    const u16* vb = qkv + (size_t)2 * MTOT * D;

    // phase 1: stage V packed [key][dim] (contiguous DMA dest)
#pragma unroll
    for (int i = 0; i < 6; i++) {
        int ch = i * 256 + tid;
        int row = ch >> 3, c = ch & 7;
        int tok = row < G ? row : win0 + (row - G);
        async16(vb + (brow + tok) * D + h * HD + c * 8,
                (u16*)KP + (i * 256 + wave * 64) * 8);
    }

    // q fragments (B-operand of S^T): wave's query tile = q0 + wave*16
    short8 bq[2];
    {
        int tok = q0 + wave * 16 + tl;
        const u16* qrow = qb + (brow + tok) * D + h * HD;
        bq[0] = *(const short8*)(qrow + quad * 8);
        bq[1] = *(const short8*)(qrow + 32 + quad * 8);
    }

    __syncthreads();   // V landed

    // phase 2: transpose Vs[key][dim] -> Vt[dim][key]
    {
        const int d = tid & 63;
#pragma unroll
        for (int i = 0; i < 6; i++) {
            int c = i * 4 + wave;   // key-chunk 0..23
            ushort8v v;
#pragma unroll
            for (int j = 0; j < 8; j++) v[j] = KP[(c * 8 + j) * 64 + d];
            *(ushort8v*)&Vt[d * 200 + c * 8] = v;
        }
    }

    __syncthreads();   // Vt ready, KP free

    // phase 3: stage K into KP, swizzled slot = g ^ (row&7)
#pragma unroll
    for (int i = 0; i < 6; i++) {
        int ch = i * 256 + tid;
        int row = ch >> 3, slot = ch & 7;
        int g = slot ^ (row & 7);
        int tok = row < G ? row : win0 + (row - G);
        async16(kb + (brow + tok) * D + h * HD + g * 8,
                (u16*)KP + (i * 256 + wave * 64) * 8);
    }

    __syncthreads();   // K landed

    // S^T = K q^T : 12 key-tiles x 1 query-tile per wave, K frags from LDS
    f32x4 s[12];
#pragma unroll
    for (int kt = 0; kt < 12; kt++) s[kt] = (f32x4)(0.0f);
#pragma unroll
    for (int kt = 0; kt < 12; kt++) {
        int row = kt * 16 + tl;
        int s0 = quad ^ (tl & 7);
        int s1 = (4 + quad) ^ (tl & 7);
        short8 a0 = *(const short8*)&KP[row * 64 + s0 * 8];
        short8 a1 = *(const short8*)&KP[row * 64 + s1 * 8];
        s[kt] = MFMA(a0, bq[0], s[kt]);
        s[kt] = MFMA(a1, bq[1], s[kt]);
    }

    // softmax over keys for query col=tl: in-lane 48 values + 2 quad shuffles
    const float c1 = 0.125f * 1.4426950408889634f;  // scale * log2(e)
    float mx = -1e30f;
#pragma unroll
    for (int kt = 0; kt < 12; kt++)
#pragma unroll
        for (int r = 0; r < 4; r++) mx = fmaxf(mx, s[kt][r]);
    mx = fmaxf(mx, __shfl_xor(mx, 16, 64));
    mx = fmaxf(mx, __shfl_xor(mx, 32, 64));
    float sum = 0.f;
#pragma unroll
    for (int kt = 0; kt < 12; kt++)
#pragma unroll
        for (int r = 0; r < 4; r++) {
            float e = exp2f((s[kt][r] - mx) * c1);
            s[kt][r] = e;
            sum += e;
        }
    sum += __shfl_xor(sum, 16, 64);
    sum += __shfl_xor(sum, 32, 64);
    float inv = 1.f / sum;

    __syncthreads();   // all waves done reading Ks before P overwrites it

    // write P: row = query (wave*16+tl), cols kt*16+quad*4..+3 (b64 packed)
    u16* Pl = (u16*)KP;
    {
        int lq = wave * 16 + tl;
#pragma unroll
        for (int kt = 0; kt < 12; kt++) {
            ushort4v p;
#pragma unroll
            for (int r = 0; r < 4; r++) p[r] = f2bf(s[kt][r] * inv);
            *(ushort4v*)&Pl[lq * 200 + kt * 16 + quad * 4] = p;
        }
    }
    __syncthreads();

    // out = P V : 1 query-tile x 4 dim-tiles per wave, K=192
    f32x4 o[4];
#pragma unroll
    for (int dt = 0; dt < 4; dt++) o[dt] = (f32x4)(0.0f);
#pragma unroll
    for (int ks = 0; ks < 6; ks++) {
        short8 pa = *(const short8*)&Pl[(wave * 16 + tl) * 200 + ks * 32 + quad * 8];
#pragma unroll
        for (int dt = 0; dt < 4; dt++) {
            short8 vv = *(const short8*)&Vt[(dt * 16 + tl) * 200 + ks * 32 + quad * 8];
            o[dt] = MFMA(pa, vv, o[dt]);
        }
    }

    // epilogue: D[m=query][n=dim], row=quad*4+r, col=tl
#pragma unroll
    for (int dt = 0; dt < 4; dt++)
#pragma unroll
        for (int r = 0; r < 4; r++) {
            int qq = q0 + wave * 16 + quad * 4 + r;
            int dim = dt * 16 + tl;
            outb[(brow + qq) * D + h * HD + dim] = f2bf(o[dt][r]);
        }
}

extern "C" void kernel_launch(void* const* d_in, const int* in_sizes, int n_in,
                              void* d_out, int out_size, void* d_ws, size_t ws_size,
                              hipStream_t stream)
{
    const float* x  = (const float*)d_in[0];
    const float* Wq = (const float*)d_in[1];
    const float* Wk = (const float*)d_in[2];
    const float* Wv = (const float*)d_in[3];
    const float* Wo = (const float*)d_in[4];

    const int M = 16384, D = 1024;   // M = B*T
    u16* xb  = (u16*)d_ws;                  // M*D
    u16* wqb = xb  + (size_t)M * D;         // D*D each (q,k,v contiguous)
    u16* wob = wqb + (size_t)3 * D * D;
    u16* qkv = wob + (size_t)D * D;         // 3*M*D (q,k,v)
    u16* att = qkv + (size_t)3 * M * D;     // M*D

    // one conversion launch: x then Wq,Wk,Wv,Wo into contiguous bf16 region
    cvt_all<<<2560, 256, 0, stream>>>(x, Wq, Wk, Wv, Wo, xb,
                                      M * D / 4, D * D / 4);

    gemm_nt<true ><<<dim3(M / 128, D / 128, 3), 256, 0, stream>>>(
        xb, wqb, wqb + (size_t)D * D, wqb + (size_t)2 * D * D, qkv, M, D, D);
    attn_win<<<dim3(4096), 256, 0, stream>>>(qkv, att);
    gemm_nt<false><<<dim3(M / 128, D / 128, 1), 256, 0, stream>>>(
        att, wob, wob, wob, d_out, M, D, D);
}

// Round 6
// 333.643 us; speedup vs baseline: 1.0493x; 1.0107x over previous
//
#include <hip/hip_runtime.h>

typedef unsigned short u16;
typedef __attribute__((ext_vector_type(8))) short short8;
typedef __attribute__((ext_vector_type(4))) float f32x4;
typedef __attribute__((ext_vector_type(16))) float f32x16;
typedef __attribute__((ext_vector_type(4))) float floatx4;
typedef __attribute__((ext_vector_type(4))) unsigned short ushort4v;
typedef __attribute__((ext_vector_type(8))) unsigned short ushort8v;

#define MFMA(a, b, c)   __builtin_amdgcn_mfma_f32_16x16x32_bf16(a, b, c, 0, 0, 0)
#define MFMA32(a, b, c) __builtin_amdgcn_mfma_f32_32x32x16_bf16(a, b, c, 0, 0, 0)

__device__ __forceinline__ u16 f2bf(float f) {
    unsigned u = __float_as_uint(f);
    u += 0x7fffu + ((u >> 16) & 1u);   // RNE
    return (u16)(u >> 16);
}

__device__ __forceinline__ void async16(const void* g, void* l) {
    __builtin_amdgcn_global_load_lds(
        (const __attribute__((address_space(1))) void*)g,
        (__attribute__((address_space(3))) void*)l, 16, 0, 0);
}

// ------- fp32 -> bf16 convert: x + 4 weight matrices in ONE launch --------
__global__ void cvt_all(const float* __restrict__ x,
                        const float* __restrict__ w0, const float* __restrict__ w1,
                        const float* __restrict__ w2, const float* __restrict__ w3,
                        u16* __restrict__ d, int nx4, int nw4) {
    int total = nx4 + 4 * nw4;
    int i = blockIdx.x * blockDim.x + threadIdx.x;
    int stride = gridDim.x * blockDim.x;
    for (; i < total; i += stride) {
        floatx4 v;
        if (i < nx4) {
            v = ((const floatx4*)x)[i];
        } else {
            int t = i - nx4;
            int w = t >> 18;             // nw4 = 2^18
            int j = t & (nw4 - 1);
            const float* s = w == 0 ? w0 : (w == 1 ? w1 : (w == 2 ? w2 : w3));
            v = ((const floatx4*)s)[j];
        }
        ushort4v o;
        o[0] = f2bf(v[0]); o[1] = f2bf(v[1]); o[2] = f2bf(v[2]); o[3] = f2bf(v[3]);
        ((ushort4v*)d)[i] = o;
    }
}

// ---------------- NT GEMM: C[M,N] = A[M,K] * B[N,K]^T ------------------
// 128x128 tile, BK=64, global_load_lds width 16, 2x2 waves, wave tile 64x64
// as 2x2 of 32x32x16 MFMA (16 MFMA/iter @8cyc vs 32 @4.85 -> -17% MFMA-pipe).
// Rows = 8 chunks of 16B, slot s of row r holds global chunk s^(r&7):
// reads distribute 8 lanes/bank-group (floor), staging stays coalesced.
template <bool BF16_OUT>
__global__ __launch_bounds__(256) void gemm_nt(
    const u16* __restrict__ A, const u16* __restrict__ B0,
    const u16* __restrict__ B1, const u16* __restrict__ B2,
    void* __restrict__ Cv, int M, int N, int K)
{
    __shared__ u16 As[128 * 64];
    __shared__ u16 Bs[128 * 64];
    const int tid = threadIdx.x;
    const int wave = tid >> 6, lane = tid & 63;
    const int l32 = lane & 31, kh = lane >> 5;   // 32-row index, k-half
    const int m0 = blockIdx.x * 128, n0 = blockIdx.y * 128;
    const int wm = wave >> 1, wn = wave & 1;
    const u16* Bm = blockIdx.z == 0 ? B0 : (blockIdx.z == 1 ? B1 : B2);
    const size_t coff = (size_t)blockIdx.z * M * N;

    f32x16 acc[2][2];
#pragma unroll
    for (int i = 0; i < 2; i++)
#pragma unroll
        for (int j = 0; j < 2; j++) acc[i][j] = (f32x16)(0.0f);

    // staging: thread owns chunk slot sslot of rows i*32+srow; global chunk
    // g = sslot ^ (srow&7) (i*32 = 0 mod 8 -> uniform over i). Row pointers
    // precomputed; only +k0 varies per iteration.
    const int srow = tid >> 3, sslot = tid & 7;
    const int gch = sslot ^ (srow & 7);
    const u16* ar[4];
    const u16* br[4];
#pragma unroll
    for (int i = 0; i < 4; i++) {
        ar[i] = A  + (size_t)(m0 + i * 32 + srow) * K + gch * 8;
        br[i] = Bm + (size_t)(n0 + i * 32 + srow) * K + gch * 8;
    }

    // fragment read address pieces (row&7 == l32&7 since tiles are 0 mod 8)
    const int rxor = l32 & 7;

    for (int k0 = 0; k0 < K; k0 += 64) {
#pragma unroll
        for (int i = 0; i < 4; i++) {
            int ldsbase = (i * 256 + wave * 64) * 8; // wave-uniform dest (u16)
            async16(ar[i] + k0, (u16*)As + ldsbase);
            async16(br[i] + k0, (u16*)Bs + ldsbase);
        }
        __syncthreads();
#pragma unroll
        for (int kc = 0; kc < 4; kc++) {
            const int rs = ((kc * 2 + kh) ^ rxor) * 8;
            short8 af[2], bg[2];
#pragma unroll
            for (int t = 0; t < 2; t++) {
                af[t] = *(const short8*)&As[(wm * 64 + t * 32 + l32) * 64 + rs];
                bg[t] = *(const short8*)&Bs[(wn * 64 + t * 32 + l32) * 64 + rs];
            }
#pragma unroll
            for (int mt = 0; mt < 2; mt++)
#pragma unroll
                for (int nt = 0; nt < 2; nt++)
                    acc[mt][nt] = MFMA32(af[mt], bg[nt], acc[mt][nt]);
        }
        __syncthreads();
    }

    // epilogue: 32x32 C/D layout col=lane&31, row=(r&3)+8*(r>>2)+4*(lane>>5)
#pragma unroll
    for (int mt = 0; mt < 2; mt++)
#pragma unroll
        for (int nt = 0; nt < 2; nt++)
#pragma unroll
            for (int r = 0; r < 16; r++) {
                int row = m0 + wm * 64 + mt * 32 + 4 * kh + (r & 3) + 8 * (r >> 2);
                int col = n0 + wn * 64 + nt * 32 + l32;
                if constexpr (BF16_OUT)
                    ((u16*)Cv)[coff + (size_t)row * N + col] = f2bf(acc[mt][nt][r]);
                else
                    ((float*)Cv)[coff + (size_t)row * N + col] = acc[mt][nt][r];
            }
}

// ---------------- fused windowed attention (R3 structure, proven) ----------
// One block per (b, h, window, half): 64 queries, 192 keys (64 global + 128
// local). V async-staged packed [key][dim] into KP, transposed LDS->LDS into
// Vt, then K async-staged into KP (XOR-swizzled); P reuses KP. S^T = K q^T so
// MFMA C-layout in-lane contiguity runs along keys (2-shuffle softmax).
__global__ __launch_bounds__(256) void attn_win(
    const u16* __restrict__ qkv, u16* __restrict__ outb)
{
    constexpr int T = 8192, D = 1024, HD = 64, G = 64, WIN = 128;
    constexpr int MTOT = 2 * T;
    __shared__ u16 Vt[64 * 200];   // V^T [dim][key], stride 200
    __shared__ u16 KP[12800];      // union: Vs[192][64] -> Ks[192][64] -> Pl[64][200]

    const int blk = blockIdx.x;
    const int half = blk & 1;
    const int nwin = (blk >> 1) & 63;
    const int h = (blk >> 7) & 15;
    const int b = blk >> 11;
    const int tid = threadIdx.x;
    const int wave = tid >> 6, lane = tid & 63;
    const int quad = lane >> 4, tl = lane & 15;
    const int win0 = nwin * WIN;
    const int q0 = win0 + half * 64;
    const size_t brow = (size_t)b * T;
    const u16* qb = qkv;
    const u16* kb = qkv + (size_t)MTOT * D;
    const u16* vb = qkv + (size_t)2 * MTOT * D;

    // phase 1: stage V packed [key][dim] (contiguous DMA dest)
#pragma unroll
    for (int i = 0; i < 6; i++) {
        int ch = i * 256 + tid;
        int row = ch >> 3, c = ch & 7;
        int tok = row < G ? row : win0 + (row - G);
        async16(vb + (brow + tok) * D + h * HD + c * 8,
                (u16*)KP + (i * 256 + wave * 64) * 8);
    }

    // q fragments (B-operand of S^T): wave's query tile = q0 + wave*16
    short8 bq[2];
    {
        int tok = q0 + wave * 16 + tl;
        const u16* qrow = qb + (brow + tok) * D + h * HD;
        bq[0] = *(const short8*)(qrow + quad * 8);
        bq[1] = *(const short8*)(qrow + 32 + quad * 8);
    }

    __syncthreads();   // V landed

    // phase 2: transpose Vs[key][dim] -> Vt[dim][key]
    {
        const int d = tid & 63;
#pragma unroll
        for (int i = 0; i < 6; i++) {
            int c = i * 4 + wave;   // key-chunk 0..23
            ushort8v v;
#pragma unroll
            for (int j = 0; j < 8; j++) v[j] = KP[(c * 8 + j) * 64 + d];
            *(ushort8v*)&Vt[d * 200 + c * 8] = v;
        }
    }

    __syncthreads();   // Vt ready, KP free

    // phase 3: stage K into KP, swizzled slot = g ^ (row&7)
#pragma unroll
    for (int i = 0; i < 6; i++) {
        int ch = i * 256 + tid;
        int row = ch >> 3, slot = ch & 7;
        int g = slot ^ (row & 7);
        int tok = row < G ? row : win0 + (row - G);
        async16(kb + (brow + tok) * D + h * HD + g * 8,
                (u16*)KP + (i * 256 + wave * 64) * 8);
    }

    __syncthreads();   // K landed

    // S^T = K q^T : 12 key-tiles x 1 query-tile per wave, K frags from LDS
    f32x4 s[12];
#pragma unroll
    for (int kt = 0; kt < 12; kt++) s[kt] = (f32x4)(0.0f);
#pragma unroll
    for (int kt = 0; kt < 12; kt++) {
        int row = kt * 16 + tl;
        int s0 = quad ^ (tl & 7);
        int s1 = (4 + quad) ^ (tl & 7);
        short8 a0 = *(const short8*)&KP[row * 64 + s0 * 8];
        short8 a1 = *(const short8*)&KP[row * 64 + s1 * 8];
        s[kt] = MFMA(a0, bq[0], s[kt]);
        s[kt] = MFMA(a1, bq[1], s[kt]);
    }

    // softmax over keys for query col=tl: in-lane 48 values + 2 quad shuffles
    const float c1 = 0.125f * 1.4426950408889634f;  // scale * log2(e)
    float mx = -1e30f;
#pragma unroll
    for (int kt = 0; kt < 12; kt++)
#pragma unroll
        for (int r = 0; r < 4; r++) mx = fmaxf(mx, s[kt][r]);
    mx = fmaxf(mx, __shfl_xor(mx, 16, 64));
    mx = fmaxf(mx, __shfl_xor(mx, 32, 64));
    float sum = 0.f;
#pragma unroll
    for (int kt = 0; kt < 12; kt++)
#pragma unroll
        for (int r = 0; r < 4; r++) {
            float e = exp2f((s[kt][r] - mx) * c1);
            s[kt][r] = e;
            sum += e;
        }
    sum += __shfl_xor(sum, 16, 64);
    sum += __shfl_xor(sum, 32, 64);
    float inv = 1.f / sum;

    __syncthreads();   // all waves done reading Ks before P overwrites it

    // write P: row = query (wave*16+tl), cols kt*16+quad*4..+3 (b64 packed)
    u16* Pl = (u16*)KP;
    {
        int lq = wave * 16 + tl;
#pragma unroll
        for (int kt = 0; kt < 12; kt++) {
            ushort4v p;
#pragma unroll
            for (int r = 0; r < 4; r++) p[r] = f2bf(s[kt][r] * inv);
            *(ushort4v*)&Pl[lq * 200 + kt * 16 + quad * 4] = p;
        }
    }
    __syncthreads();

    // out = P V : 1 query-tile x 4 dim-tiles per wave, K=192
    f32x4 o[4];
#pragma unroll
    for (int dt = 0; dt < 4; dt++) o[dt] = (f32x4)(0.0f);
#pragma unroll
    for (int ks = 0; ks < 6; ks++) {
        short8 pa = *(const short8*)&Pl[(wave * 16 + tl) * 200 + ks * 32 + quad * 8];
#pragma unroll
        for (int dt = 0; dt < 4; dt++) {
            short8 vv = *(const short8*)&Vt[(dt * 16 + tl) * 200 + ks * 32 + quad * 8];
            o[dt] = MFMA(pa, vv, o[dt]);
        }
    }

    // epilogue: D[m=query][n=dim], row=quad*4+r, col=tl
#pragma unroll
    for (int dt = 0; dt < 4; dt++)
#pragma unroll
        for (int r = 0; r < 4; r++) {
            int qq = q0 + wave * 16 + quad * 4 + r;
            int dim = dt * 16 + tl;
            outb[(brow + qq) * D + h * HD + dim] = f2bf(o[dt][r]);
        }
}

extern "C" void kernel_launch(void* const* d_in, const int* in_sizes, int n_in,
                              void* d_out, int out_size, void* d_ws, size_t ws_size,
                              hipStream_t stream)
{
    const float* x  = (const float*)d_in[0];
    const float* Wq = (const float*)d_in[1];
    const float* Wk = (const float*)d_in[2];
    const float* Wv = (const float*)d_in[3];
    const float* Wo = (const float*)d_in[4];

    const int M = 16384, D = 1024;   // M = B*T
    u16* xb  = (u16*)d_ws;                  // M*D
    u16* wqb = xb  + (size_t)M * D;         // D*D each (q,k,v contiguous)
    u16* wob = wqb + (size_t)3 * D * D;
    u16* qkv = wob + (size_t)D * D;         // 3*M*D (q,k,v)
    u16* att = qkv + (size_t)3 * M * D;     // M*D

    cvt_all<<<2560, 256, 0, stream>>>(x, Wq, Wk, Wv, Wo, xb,
                                      M * D / 4, D * D / 4);

    gemm_nt<true ><<<dim3(M / 128, D / 128, 3), 256, 0, stream>>>(
        xb, wqb, wqb + (size_t)D * D, wqb + (size_t)2 * D * D, qkv, M, D, D);
    attn_win<<<dim3(4096), 256, 0, stream>>>(qkv, att);
    gemm_nt<false><<<dim3(M / 128, D / 128, 1), 256, 0, stream>>>(
        att, wob, wob, wob, d_out, M, D, D);
}